// Round 11
// baseline (144.262 us; speedup 1.0000x reference)
//
#include <hip/hip_runtime.h>
#include <hip/hip_bf16.h>
#include <stdint.h>

typedef __attribute__((ext_vector_type(8))) short bf16x8;
typedef __attribute__((ext_vector_type(4))) float f32x4;
typedef __attribute__((ext_vector_type(4))) unsigned int u32x4;

#define NB 256
#define CC 128

static __device__ __forceinline__ unsigned int cvt_pk_bf16(float lo, float hi) {
  unsigned int r;
  asm("v_cvt_pk_bf16_f32 %0, %1, %2" : "=v"(r) : "v"(lo), "v"(hi));
  return r;
}
static __device__ __forceinline__ uint16_t f2bf(float f) {
  unsigned u = __builtin_bit_cast(unsigned, f);
  return (uint16_t)((u + 0x7FFFu + ((u >> 16) & 1u)) >> 16);
}
static __device__ __forceinline__ f32x4 nt_load(const void* p) {
  return __builtin_nontemporal_load((const f32x4*)p);
}

// ---- k_prep: blocks 0..127 weight prep; blocks 128..1151 node prep (2 rows each)
__global__ void k_prep(const float* __restrict__ W_edge, const float* __restrict__ b_edge,
                       const float* __restrict__ W_pre, const float* __restrict__ b_pre,
                       const float* __restrict__ x,
                       uint16_t* __restrict__ wct, float* __restrict__ bc2,
                       float* __restrict__ At, unsigned* __restrict__ bvl) {
  const int c = threadIdx.x;  // 0..127
  if (blockIdx.x < 128) {
    const int k = blockIdx.x;   // input channel
    float acc = 0.f;
    for (int q = 0; q < CC; ++q)
      acc += W_edge[k * CC + q] * W_pre[(2 * CC + q) * CC + c];
    wct[c * CC + k] = f2bf(acc);                        // (W_edge@W3)^T, bf16
    if (k == 0) {
      float a2 = b_pre[c];
      for (int q = 0; q < CC; ++q) a2 += b_edge[q] * W_pre[(2 * CC + q) * CC + c];
      bc2[c] = a2;
    }
  } else {
    const int m0 = (blockIdx.x - 128) * 2;   // 2 node rows per block
    __shared__ float xs[2][CC];
    xs[0][c] = x[(size_t)m0 * CC + c];
    xs[1][c] = x[(size_t)(m0 + 1) * CC + c];
    __syncthreads();
    float a0 = 0.f, a1 = 0.f, v0 = 0.f, v1 = 0.f;
#pragma unroll 4
    for (int k = 0; k < CC; ++k) {
      const float w1 = W_pre[k * CC + c];
      const float w2 = W_pre[(CC + k) * CC + c];
      a0 += xs[0][k] * w1; a1 += xs[1][k] * w1;
      v0 += xs[0][k] * w2; v1 += xs[1][k] * w2;
    }
    At[(size_t)m0 * CC + c] = a0;       At[(size_t)(m0 + 1) * CC + c] = a1;
    // pack bvl[row][wv(2b)][lr(4b)] = {bf16(ch=wv*32+lr), bf16(ch=wv*32+16+lr)}
    const float p0 = __shfl_down(v0, 16);
    const float p1 = __shfl_down(v1, 16);
    if ((c & 31) < 16) {
      const int di = (c >> 5) * 16 + (c & 15);
      bvl[(size_t)m0 * 64 + di]       = ((unsigned)f2bf(p0) << 16) | f2bf(v0);
      bvl[(size_t)(m0 + 1) * 64 + di] = ((unsigned)f2bf(p1) << 16) | f2bf(v1);
    }
  }
}

// ---- k1: fused edge-GEMM + PNA reduction, 32-row phases, NT edge loads ----
__global__ __launch_bounds__(256, 3) void k_edge(
    const float* __restrict__ edge, const uint16_t* __restrict__ wct,
    const unsigned* __restrict__ bvl, const float* __restrict__ At,
    const float* __restrict__ bc2, float* __restrict__ agg) {
  __shared__ __align__(16) char ebuf[2][32 * 272];    // 32 rows x 128 bf16, padded
  __shared__ __align__(16) char bvbuf[2][32 * 272];   // 32 rows x 64 u32 pairs, padded

  const int blk  = blockIdx.x;         // b*256 + i
  const int b    = blk >> 8;
  const int tid  = threadIdx.x;
  const int lane = tid & 63;
  const int wv   = tid >> 6;           // 0..3
  const int g    = lane >> 4;          // 0..3
  const int lr   = lane & 15;
  const int cb   = wv * 32;            // 32 output channels per wave

  // Resident B fragments from wct
  bf16x8 bfr[2][4];
#pragma unroll
  for (int t = 0; t < 2; ++t) {
    const uint16_t* p1 = wct + (cb + t * 16 + lr) * CC + g * 8;
#pragma unroll
    for (int ks = 0; ks < 4; ++ks)
      bfr[t][ks] = *(const bf16x8*)(p1 + ks * 32);
  }
  asm volatile("s_waitcnt vmcnt(0)" ::: "memory");   // FIFO now holds only stage loads

  const char* egbase  = (const char*)(edge + (size_t)blk * (NB * CC));
  const char* bvgbase = (const char*)(bvl + (size_t)b * (NB * 64));
  // staging dest: thread covers 64B global e (16 fp32 -> 32B bf16) and 32B bv
  const int sdst = (tid >> 3) * 272 + (tid & 7) * 32;

  f32x4 eA[4], eB[4];
  u32x4 vA0, vA1, vB0, vB1;

  auto LOADA = [&](int t) {
    const char* eg = egbase + (size_t)t * 16384 + tid * 64;
#pragma unroll
    for (int k = 0; k < 4; ++k) eA[k] = nt_load(eg + k * 16);
    const char* bg = bvgbase + (size_t)t * 8192 + tid * 32;
    vA0 = *(const u32x4*)(bg);
    vA1 = *(const u32x4*)(bg + 16);
  };
  auto LOADB = [&](int t) {
    const char* eg = egbase + (size_t)t * 16384 + tid * 64;
#pragma unroll
    for (int k = 0; k < 4; ++k) eB[k] = nt_load(eg + k * 16);
    const char* bg = bvgbase + (size_t)t * 8192 + tid * 32;
    vB0 = *(const u32x4*)(bg);
    vB1 = *(const u32x4*)(bg + 16);
  };
  auto STORE = [&](char* eb_, char* bb_, const f32x4* E, const u32x4& v0, const u32x4& v1) {
    u32x4 w0, w1;
    w0.x = cvt_pk_bf16(E[0].x, E[0].y); w0.y = cvt_pk_bf16(E[0].z, E[0].w);
    w0.z = cvt_pk_bf16(E[1].x, E[1].y); w0.w = cvt_pk_bf16(E[1].z, E[1].w);
    w1.x = cvt_pk_bf16(E[2].x, E[2].y); w1.y = cvt_pk_bf16(E[2].z, E[2].w);
    w1.z = cvt_pk_bf16(E[3].x, E[3].y); w1.w = cvt_pk_bf16(E[3].z, E[3].w);
    *(u32x4*)(eb_ + sdst) = w0;
    *(u32x4*)(eb_ + sdst + 16) = w1;
    *(u32x4*)(bb_ + sdst) = v0;
    *(u32x4*)(bb_ + sdst + 16) = v1;
  };

  float sum0 = 0.f, sum1 = 0.f, ssq0 = 0.f, ssq1 = 0.f;
  float mn0 = 1e30f, mn1 = 1e30f, mx0 = -1e30f, mx1 = -1e30f;

  auto COMPUTE = [&](const char* eb_, const char* bb_) {
#pragma unroll
    for (int rg = 0; rg < 2; ++rg) {
      const char* eb = eb_ + (rg * 16 + lr) * 272;
      f32x4 acc0 = {0.f, 0.f, 0.f, 0.f}, acc1 = {0.f, 0.f, 0.f, 0.f};
#pragma unroll
      for (int ks = 0; ks < 4; ++ks) {
        bf16x8 af = *(const bf16x8*)(eb + g * 16 + ks * 64);
        acc0 = __builtin_amdgcn_mfma_f32_16x16x32_bf16(af, bfr[0][ks], acc0, 0, 0, 0);
        acc1 = __builtin_amdgcn_mfma_f32_16x16x32_bf16(af, bfr[1][ks], acc1, 0, 0, 0);
      }
#pragma unroll
      for (int r = 0; r < 4; ++r) {
        const int row = rg * 16 + g * 4 + r;
        const unsigned pv = *(const unsigned*)(bb_ + row * 272 + wv * 64 + lr * 4);
        const float bv0 = __builtin_bit_cast(float, pv << 16);
        const float bv1 = __builtin_bit_cast(float, pv & 0xffff0000u);
        float s0 = acc0[r] + bv0;
        float s1 = acc1[r] + bv1;
        sum0 += s0; ssq0 = fmaf(s0, s0, ssq0);
        mn0 = fminf(mn0, s0); mx0 = fmaxf(mx0, s0);
        sum1 += s1; ssq1 = fmaf(s1, s1, ssq1);
        mn1 = fminf(mn1, s1); mx1 = fmaxf(mx1, s1);
      }
    }
  };

  LOADA(0); LOADB(1);
  __builtin_amdgcn_sched_barrier(0);

#pragma unroll 1
  for (int tt = 0; tt < 8; tt += 2) {
    // ---- phase tt : regs A -> buf0
    __builtin_amdgcn_s_barrier();                       // WAR: buf0 free
    asm volatile("s_waitcnt vmcnt(6)" ::: "memory");    // A landed (B in flight)
    __builtin_amdgcn_sched_barrier(0);
    STORE(ebuf[0], bvbuf[0], eA, vA0, vA1);
    asm volatile("s_waitcnt lgkmcnt(0)" ::: "memory");
    __builtin_amdgcn_sched_barrier(0);
    __builtin_amdgcn_s_barrier();                       // RAW: buf0 visible
    if (tt + 2 < 8) LOADA(tt + 2);
    __builtin_amdgcn_sched_barrier(0);
    COMPUTE(ebuf[0], bvbuf[0]);
    // ---- phase tt+1 : regs B -> buf1
    __builtin_amdgcn_s_barrier();                       // WAR: buf1 free
    if (tt < 6) { asm volatile("s_waitcnt vmcnt(6)" ::: "memory"); }
    else        { asm volatile("s_waitcnt vmcnt(0)" ::: "memory"); }
    __builtin_amdgcn_sched_barrier(0);
    STORE(ebuf[1], bvbuf[1], eB, vB0, vB1);
    asm volatile("s_waitcnt lgkmcnt(0)" ::: "memory");
    __builtin_amdgcn_sched_barrier(0);
    __builtin_amdgcn_s_barrier();                       // RAW: buf1 visible
    if (tt + 3 < 8) LOADB(tt + 3);
    __builtin_amdgcn_sched_barrier(0);
    COMPUTE(ebuf[1], bvbuf[1]);
  }

  // reduce across the 4 row-groups (lane bits 4,5)
#pragma unroll
  for (int m = 16; m <= 32; m <<= 1) {
    sum0 += __shfl_xor(sum0, m); ssq0 += __shfl_xor(ssq0, m);
    mn0 = fminf(mn0, __shfl_xor(mn0, m)); mx0 = fmaxf(mx0, __shfl_xor(mx0, m));
    sum1 += __shfl_xor(sum1, m); ssq1 += __shfl_xor(ssq1, m);
    mn1 = fminf(mn1, __shfl_xor(mn1, m)); mx1 = fmaxf(mx1, __shfl_xor(mx1, m));
  }
  if (g == 0) {
#pragma unroll
    for (int t = 0; t < 2; ++t) {
      const int col = cb + t * 16 + lr;
      const float s   = t ? sum1 : sum0;
      const float q   = t ? ssq1 : ssq0;
      const float mnv = t ? mn1 : mn0;
      const float mxv = t ? mx1 : mx0;
      const float tt2 = At[blk * CC + col] + bc2[col];
      const float mean = s * (1.f / NB);
      const float var = q * (1.f / NB) - mean * mean;
      const float sd = sqrtf(fmaxf(var, 0.f) + 1e-5f);
      float* ap = agg + (size_t)blk * (4 * CC) + col;
      ap[0]      = tt2 + mean;
      ap[CC]     = tt2 + mnv;
      ap[2 * CC] = tt2 + mxv;
      ap[3 * CC] = sd;     // std is invariant to the j-constant term
    }
  }
}

// ---- k2: out = [x,agg]@W_post + b_post ; out@W_lin + b_lin ; per-block GN partials ----
__global__ __launch_bounds__(256) void k_post(
    const float* __restrict__ x, const float* __restrict__ agg,
    const float* __restrict__ W_post, const float* __restrict__ b_post,
    const float* __restrict__ W_lin, const float* __restrict__ b_lin,
    float* __restrict__ outl, float* __restrict__ psum, float* __restrict__ psq) {
  __shared__ float hx[4][5 * CC];
  __shared__ float o1[4][CC];
  __shared__ float pl[4][CC];
  const int blk = blockIdx.x;
  const int t = threadIdx.x;
  const int row0 = blk * 4;

  for (int idx = t; idx < 4 * 5 * CC; idx += 256) {
    int r = idx / (5 * CC), col = idx - r * (5 * CC);
    hx[r][col] = (col < CC) ? x[(size_t)(row0 + r) * CC + col]
                            : agg[(size_t)(row0 + r) * (4 * CC) + (col - CC)];
  }
  __syncthreads();

  const int c = t & (CC - 1);
  const int rh = t >> 7;  // 0/1
  float acc[2] = {b_post[c], b_post[c]};
  for (int k = 0; k < 5 * CC; k += 4) {
    float w0 = W_post[(k + 0) * CC + c];
    float w1 = W_post[(k + 1) * CC + c];
    float w2 = W_post[(k + 2) * CC + c];
    float w3 = W_post[(k + 3) * CC + c];
#pragma unroll
    for (int i = 0; i < 2; ++i) {
      const f32x4 h4 = *(const f32x4*)&hx[2 * i + rh][k];
      acc[i] += h4.x * w0 + h4.y * w1 + h4.z * w2 + h4.w * w3;
    }
  }
#pragma unroll
  for (int i = 0; i < 2; ++i) o1[2 * i + rh][c] = acc[i];
  __syncthreads();

  float a2[2] = {b_lin[c], b_lin[c]};
  for (int k = 0; k < CC; k += 4) {
    float w0 = W_lin[(k + 0) * CC + c];
    float w1 = W_lin[(k + 1) * CC + c];
    float w2 = W_lin[(k + 2) * CC + c];
    float w3 = W_lin[(k + 3) * CC + c];
#pragma unroll
    for (int i = 0; i < 2; ++i) {
      const f32x4 h4 = *(const f32x4*)&o1[2 * i + rh][k];
      a2[i] += h4.x * w0 + h4.y * w1 + h4.z * w2 + h4.w * w3;
    }
  }
  float ps = 0.f, pq = 0.f;
#pragma unroll
  for (int i = 0; i < 2; ++i) {
    outl[(size_t)(row0 + 2 * i + rh) * CC + c] = a2[i];
    ps += a2[i]; pq += a2[i] * a2[i];
  }
  pl[rh][c] = ps; pl[2 + rh][c] = pq;
  __syncthreads();
  if (t < CC) {
    psum[blk * CC + t] = pl[0][t] + pl[1][t];
    psq[blk * CC + t]  = pl[2][t] + pl[3][t];
  }
}

// ---- k3: fused GraphNorm stats + normalize + relu + residual ----
__global__ __launch_bounds__(256) void k_apply(
    const float* __restrict__ psum, const float* __restrict__ psq,
    const float* __restrict__ outl, const float* __restrict__ x,
    const float* __restrict__ gw, const float* __restrict__ gb,
    const float* __restrict__ alpha, float* __restrict__ y) {
  __shared__ float red[4][CC];
  __shared__ float smu[CC], siv[CC];
  const int t = threadIdx.x;
  const int c = t & (CC - 1);
  const int h = t >> 7;   // 0/1
  float s = 0.f, q = 0.f;
#pragma unroll 4
  for (int i = 0; i < 256; ++i) {
    const int r = h * 256 + i;
    s += psum[r * CC + c];
    q += psq[r * CC + c];
  }
  red[h][c] = s; red[2 + h][c] = q;
  __syncthreads();
  if (t < CC) {
    const float ss = red[0][t] + red[1][t];
    const float qq = red[2][t] + red[3][t];
    const float mu = ss * (1.f / 2048.f);
    const float ex2 = qq * (1.f / 2048.f);
    const float amu = alpha[t] * mu;
    const float v = ex2 - 2.f * amu * mu + amu * amu;
    smu[t] = amu;
    siv[t] = gw[t] / sqrtf(v + 1e-5f);
  }
  __syncthreads();
  const int row0 = blockIdx.x * 8;
#pragma unroll
  for (int r = 0; r < 8; r += 2) {
    const int idx = (row0 + r + h) * CC + c;
    const float o = outl[idx];
    const float val = (o - smu[c]) * siv[c] + gb[c];
    y[idx] = fmaxf(val, 0.f) + x[idx];
  }
}

extern "C" void kernel_launch(void* const* d_in, const int* in_sizes, int n_in,
                              void* d_out, int out_size, void* d_ws, size_t ws_size,
                              hipStream_t stream) {
  const float* x      = (const float*)d_in[0];
  const float* edge   = (const float*)d_in[1];
  const float* W_edge = (const float*)d_in[2];
  const float* b_edge = (const float*)d_in[3];
  const float* W_pre  = (const float*)d_in[4];
  const float* b_pre  = (const float*)d_in[5];
  const float* W_post = (const float*)d_in[6];
  const float* b_post = (const float*)d_in[7];
  const float* W_lin  = (const float*)d_in[8];
  const float* b_lin  = (const float*)d_in[9];
  const float* gw     = (const float*)d_in[10];
  const float* gb     = (const float*)d_in[11];
  const float* alpha  = (const float*)d_in[12];
  float* y = (float*)d_out;

  float* wsf = (float*)d_ws;
  float* bc2   = wsf;                 // 128
  float* At    = wsf + 128;           // 2048*128 -> ends 262272
  float* agg   = wsf + 262272;        // 2048*512 -> ends 1310848
  float* outl  = wsf + 1310848;       // 2048*128 -> ends 1572992
  float* psum  = wsf + 1572992;       // 512*128 -> ends 1638528
  float* psq   = wsf + 1638528;       // 512*128 -> ends 1704064
  uint16_t* wct = (uint16_t*)(wsf + 1704064);  // 16384 bf16 -> ends 1712256
  unsigned* bvl = (unsigned*)(wsf + 1712256);  // 2048*64 u32 -> ends 1843328

  k_prep<<<1152, 128, 0, stream>>>(W_edge, b_edge, W_pre, b_pre, x, wct, bc2, At, bvl);
  k_edge<<<2048, 256, 0, stream>>>(edge, wct, bvl, At, bc2, agg);
  k_post<<<512, 256, 0, stream>>>(x, agg, W_post, b_post, W_lin, b_lin, outl, psum, psq);
  k_apply<<<256, 256, 0, stream>>>(psum, psq, outl, x, gw, gb, alpha, y);
}

// Round 12
// 90.349 us; speedup vs baseline: 1.5967x; 1.5967x over previous
//
#include <hip/hip_runtime.h>
#include <hip/hip_bf16.h>
#include <stdint.h>

typedef __attribute__((ext_vector_type(8))) short bf16x8;
typedef __attribute__((ext_vector_type(4))) float f32x4;
typedef __attribute__((ext_vector_type(4))) unsigned int u32x4;

#define NB 256
#define CC 128

static __device__ __forceinline__ unsigned int cvt_pk_bf16(float lo, float hi) {
  unsigned int r;
  asm("v_cvt_pk_bf16_f32 %0, %1, %2" : "=v"(r) : "v"(lo), "v"(hi));
  return r;
}
static __device__ __forceinline__ uint16_t f2bf(float f) {
  unsigned u = __builtin_bit_cast(unsigned, f);
  return (uint16_t)((u + 0x7FFFu + ((u >> 16) & 1u)) >> 16);
}

// ---- k_prep: [0,128) wct/bc2 ; [128,1152) node prep ; [1152,1280) W_comb ----
__global__ void k_prep(const float* __restrict__ W_edge, const float* __restrict__ b_edge,
                       const float* __restrict__ W_pre, const float* __restrict__ b_pre,
                       const float* __restrict__ W_post, const float* __restrict__ b_post,
                       const float* __restrict__ W_lin, const float* __restrict__ b_lin,
                       const float* __restrict__ x,
                       uint16_t* __restrict__ wct, float* __restrict__ bc2,
                       float* __restrict__ At, unsigned* __restrict__ bvl,
                       uint16_t* __restrict__ wcombT, float* __restrict__ bcomb) {
  __shared__ float sh[32 * 128];   // 16 KB, shared by branches
  const int c = threadIdx.x;  // 0..127
  if (blockIdx.x < 128) {
    const int k = blockIdx.x;   // input channel
    float acc = 0.f;
    for (int q = 0; q < CC; ++q)
      acc += W_edge[k * CC + q] * W_pre[(2 * CC + q) * CC + c];
    wct[c * CC + k] = f2bf(acc);                        // (W_edge@W3)^T, bf16
    if (k == 0) {
      float a2 = b_pre[c];
      for (int q = 0; q < CC; ++q) a2 += b_edge[q] * W_pre[(2 * CC + q) * CC + c];
      bc2[c] = a2;
    }
  } else if (blockIdx.x < 1152) {
    const int m0 = (blockIdx.x - 128) * 2;   // 2 node rows per block
    float* xs0 = sh; float* xs1 = sh + CC;
    xs0[c] = x[(size_t)m0 * CC + c];
    xs1[c] = x[(size_t)(m0 + 1) * CC + c];
    __syncthreads();
    float a0 = 0.f, a1 = 0.f, v0 = 0.f, v1 = 0.f;
#pragma unroll 4
    for (int k = 0; k < CC; ++k) {
      const float w1 = W_pre[k * CC + c];
      const float w2 = W_pre[(CC + k) * CC + c];
      a0 += xs0[k] * w1; a1 += xs1[k] * w1;
      v0 += xs0[k] * w2; v1 += xs1[k] * w2;
    }
    At[(size_t)m0 * CC + c] = a0;       At[(size_t)(m0 + 1) * CC + c] = a1;
    const float p0 = __shfl_down(v0, 16);
    const float p1 = __shfl_down(v1, 16);
    if ((c & 31) < 16) {
      const int di = (c >> 5) * 16 + (c & 15);
      bvl[(size_t)m0 * 64 + di]       = ((unsigned)f2bf(p0) << 16) | f2bf(v0);
      bvl[(size_t)(m0 + 1) * 64 + di] = ((unsigned)f2bf(p1) << 16) | f2bf(v1);
    }
  } else {
    // W_comb[kk][c] = sum_q W_post[kk][q] * W_lin[q][c]; 5 kk per block
    const int kb = (blockIdx.x - 1152) * 5;
    float acc[5] = {0.f, 0.f, 0.f, 0.f, 0.f};
    float bacc = 0.f;
    for (int qc = 0; qc < 4; ++qc) {
      __syncthreads();
      for (int idx = c; idx < 32 * 128; idx += 128)
        sh[idx] = W_lin[qc * 4096 + idx];
      __syncthreads();
#pragma unroll 1
      for (int q = 0; q < 32; ++q) {
        const float wlv = sh[q * 128 + c];
        const int qg = qc * 32 + q;
#pragma unroll
        for (int k = 0; k < 5; ++k)
          acc[k] += W_post[(size_t)(kb + k) * 128 + qg] * wlv;
        bacc += b_post[qg] * wlv;
      }
    }
#pragma unroll
    for (int k = 0; k < 5; ++k)
      wcombT[(size_t)c * 640 + kb + k] = f2bf(acc[k]);
    if (blockIdx.x == 1152) bcomb[c] = bacc + b_lin[c];
  }
}

// ---- k1: fused edge-GEMM + PNA reduction, 32-row phases, XCD-swizzled ----
__global__ __launch_bounds__(256, 3) void k_edge(
    const float* __restrict__ edge, const uint16_t* __restrict__ wct,
    const unsigned* __restrict__ bvl, const float* __restrict__ At,
    const float* __restrict__ bc2, float* __restrict__ agg) {
  __shared__ __align__(16) char ebuf[2][32 * 272];    // 32 rows x 128 bf16, padded
  __shared__ __align__(16) char bvbuf[2][32 * 272];   // 32 rows x 64 u32 pairs, padded

  const int bid  = blockIdx.x;
  const int blk  = ((bid & 7) << 8) + (bid >> 3);   // XCD k owns batch k (bijective)
  const int b    = blk >> 8;
  const int tid  = threadIdx.x;
  const int lane = tid & 63;
  const int wv   = tid >> 6;           // 0..3
  const int g    = lane >> 4;          // 0..3
  const int lr   = lane & 15;
  const int cb   = wv * 32;            // 32 output channels per wave

  bf16x8 bfr[2][4];
#pragma unroll
  for (int t = 0; t < 2; ++t) {
    const uint16_t* p1 = wct + (cb + t * 16 + lr) * CC + g * 8;
#pragma unroll
    for (int ks = 0; ks < 4; ++ks)
      bfr[t][ks] = *(const bf16x8*)(p1 + ks * 32);
  }
  asm volatile("s_waitcnt vmcnt(0)" ::: "memory");   // FIFO now holds only stage loads

  const char* egbase  = (const char*)(edge + (size_t)blk * (NB * CC));
  const char* bvgbase = (const char*)(bvl + (size_t)b * (NB * 64));
  const int sdst = (tid >> 3) * 272 + (tid & 7) * 32;

  f32x4 eA[4], eB[4];
  u32x4 vA0, vA1, vB0, vB1;

  auto LOADA = [&](int t) {
    const char* eg = egbase + (size_t)t * 16384 + tid * 64;
#pragma unroll
    for (int k = 0; k < 4; ++k) eA[k] = *(const f32x4*)(eg + k * 16);
    const char* bg = bvgbase + (size_t)t * 8192 + tid * 32;
    vA0 = *(const u32x4*)(bg);
    vA1 = *(const u32x4*)(bg + 16);
  };
  auto LOADB = [&](int t) {
    const char* eg = egbase + (size_t)t * 16384 + tid * 64;
#pragma unroll
    for (int k = 0; k < 4; ++k) eB[k] = *(const f32x4*)(eg + k * 16);
    const char* bg = bvgbase + (size_t)t * 8192 + tid * 32;
    vB0 = *(const u32x4*)(bg);
    vB1 = *(const u32x4*)(bg + 16);
  };
  auto STORE = [&](char* eb_, char* bb_, const f32x4* E, const u32x4& v0, const u32x4& v1) {
    u32x4 w0, w1;
    w0.x = cvt_pk_bf16(E[0].x, E[0].y); w0.y = cvt_pk_bf16(E[0].z, E[0].w);
    w0.z = cvt_pk_bf16(E[1].x, E[1].y); w0.w = cvt_pk_bf16(E[1].z, E[1].w);
    w1.x = cvt_pk_bf16(E[2].x, E[2].y); w1.y = cvt_pk_bf16(E[2].z, E[2].w);
    w1.z = cvt_pk_bf16(E[3].x, E[3].y); w1.w = cvt_pk_bf16(E[3].z, E[3].w);
    *(u32x4*)(eb_ + sdst) = w0;
    *(u32x4*)(eb_ + sdst + 16) = w1;
    *(u32x4*)(bb_ + sdst) = v0;
    *(u32x4*)(bb_ + sdst + 16) = v1;
  };

  float sum0 = 0.f, sum1 = 0.f, ssq0 = 0.f, ssq1 = 0.f;
  float mn0 = 1e30f, mn1 = 1e30f, mx0 = -1e30f, mx1 = -1e30f;

  auto COMPUTE = [&](const char* eb_, const char* bb_) {
#pragma unroll
    for (int rg = 0; rg < 2; ++rg) {
      const char* eb = eb_ + (rg * 16 + lr) * 272;
      f32x4 acc0 = {0.f, 0.f, 0.f, 0.f}, acc1 = {0.f, 0.f, 0.f, 0.f};
#pragma unroll
      for (int ks = 0; ks < 4; ++ks) {
        bf16x8 af = *(const bf16x8*)(eb + g * 16 + ks * 64);
        acc0 = __builtin_amdgcn_mfma_f32_16x16x32_bf16(af, bfr[0][ks], acc0, 0, 0, 0);
        acc1 = __builtin_amdgcn_mfma_f32_16x16x32_bf16(af, bfr[1][ks], acc1, 0, 0, 0);
      }
#pragma unroll
      for (int r = 0; r < 4; ++r) {
        const int row = rg * 16 + g * 4 + r;
        const unsigned pv = *(const unsigned*)(bb_ + row * 272 + wv * 64 + lr * 4);
        const float bv0 = __builtin_bit_cast(float, pv << 16);
        const float bv1 = __builtin_bit_cast(float, pv & 0xffff0000u);
        float s0 = acc0[r] + bv0;
        float s1 = acc1[r] + bv1;
        sum0 += s0; ssq0 = fmaf(s0, s0, ssq0);
        mn0 = fminf(mn0, s0); mx0 = fmaxf(mx0, s0);
        sum1 += s1; ssq1 = fmaf(s1, s1, ssq1);
        mn1 = fminf(mn1, s1); mx1 = fmaxf(mx1, s1);
      }
    }
  };

  LOADA(0); LOADB(1);
  __builtin_amdgcn_sched_barrier(0);

#pragma unroll 1
  for (int tt = 0; tt < 8; tt += 2) {
    __builtin_amdgcn_s_barrier();                       // WAR: buf0 free
    asm volatile("s_waitcnt vmcnt(6)" ::: "memory");    // A landed (B in flight)
    __builtin_amdgcn_sched_barrier(0);
    STORE(ebuf[0], bvbuf[0], eA, vA0, vA1);
    asm volatile("s_waitcnt lgkmcnt(0)" ::: "memory");
    __builtin_amdgcn_sched_barrier(0);
    __builtin_amdgcn_s_barrier();                       // RAW: buf0 visible
    if (tt + 2 < 8) LOADA(tt + 2);
    __builtin_amdgcn_sched_barrier(0);
    COMPUTE(ebuf[0], bvbuf[0]);
    __builtin_amdgcn_s_barrier();                       // WAR: buf1 free
    if (tt < 6) { asm volatile("s_waitcnt vmcnt(6)" ::: "memory"); }
    else        { asm volatile("s_waitcnt vmcnt(0)" ::: "memory"); }
    __builtin_amdgcn_sched_barrier(0);
    STORE(ebuf[1], bvbuf[1], eB, vB0, vB1);
    asm volatile("s_waitcnt lgkmcnt(0)" ::: "memory");
    __builtin_amdgcn_sched_barrier(0);
    __builtin_amdgcn_s_barrier();                       // RAW: buf1 visible
    if (tt + 3 < 8) LOADB(tt + 3);
    __builtin_amdgcn_sched_barrier(0);
    COMPUTE(ebuf[1], bvbuf[1]);
  }

#pragma unroll
  for (int m = 16; m <= 32; m <<= 1) {
    sum0 += __shfl_xor(sum0, m); ssq0 += __shfl_xor(ssq0, m);
    mn0 = fminf(mn0, __shfl_xor(mn0, m)); mx0 = fmaxf(mx0, __shfl_xor(mx0, m));
    sum1 += __shfl_xor(sum1, m); ssq1 += __shfl_xor(ssq1, m);
    mn1 = fminf(mn1, __shfl_xor(mn1, m)); mx1 = fmaxf(mx1, __shfl_xor(mx1, m));
  }
  if (g == 0) {
#pragma unroll
    for (int t = 0; t < 2; ++t) {
      const int col = cb + t * 16 + lr;
      const float s   = t ? sum1 : sum0;
      const float q   = t ? ssq1 : ssq0;
      const float mnv = t ? mn1 : mn0;
      const float mxv = t ? mx1 : mx0;
      const float tt2 = At[blk * CC + col] + bc2[col];
      const float mean = s * (1.f / NB);
      const float var = q * (1.f / NB) - mean * mean;
      const float sd = sqrtf(fmaxf(var, 0.f) + 1e-5f);
      float* ap = agg + (size_t)blk * (4 * CC) + col;
      ap[0]      = tt2 + mean;
      ap[CC]     = tt2 + mnv;
      ap[2 * CC] = tt2 + mxv;
      ap[3 * CC] = sd;
    }
  }
}

// ---- k2: out = [x,agg] @ W_comb + b_comb via MFMA ; per-block GN partials ----
// 128 blocks x 16 rows; A = bf16 rows in padded LDS; B = W_comb^T from L2.
__global__ __launch_bounds__(256) void k_post(
    const float* __restrict__ x, const float* __restrict__ agg,
    const uint16_t* __restrict__ wcombT, const float* __restrict__ bcomb,
    float* __restrict__ outl, float* __restrict__ psum, float* __restrict__ psq) {
  __shared__ __align__(16) char hbuf[16 * 1296];   // 16 rows x 640 bf16, padded
  const int blk = blockIdx.x, tid = threadIdx.x;
  const int lane = tid & 63, wv = tid >> 6, g = lane >> 4, lr = lane & 15;
  const int cb = wv * 32, row0 = blk * 16;

  for (int u = tid; u < 2560; u += 256) {          // 16 rows x 160 f32x4 units
    const int row = u / 160, cu = u - row * 160;
    f32x4 v;
    if (cu < 32) v = *(const f32x4*)(x + (size_t)(row0 + row) * 128 + cu * 4);
    else         v = *(const f32x4*)(agg + (size_t)(row0 + row) * 512 + (cu - 32) * 4);
    unsigned* d = (unsigned*)(hbuf + row * 1296 + cu * 8);
    d[0] = cvt_pk_bf16(v.x, v.y);
    d[1] = cvt_pk_bf16(v.z, v.w);
  }
  __syncthreads();

  const uint16_t* wb0 = wcombT + (size_t)(cb + lr) * 640 + g * 8;
  const uint16_t* wb1 = wcombT + (size_t)(cb + 16 + lr) * 640 + g * 8;
  f32x4 acc0 = {0.f, 0.f, 0.f, 0.f}, acc1 = {0.f, 0.f, 0.f, 0.f};
#pragma unroll
  for (int ck = 0; ck < 5; ++ck) {                 // K chunks of 128
#pragma unroll
    for (int ks = 0; ks < 4; ++ks) {
      bf16x8 af = *(const bf16x8*)(hbuf + lr * 1296 + ck * 256 + ks * 64 + g * 16);
      bf16x8 b0 = *(const bf16x8*)(wb0 + ck * 128 + ks * 32);
      bf16x8 b1 = *(const bf16x8*)(wb1 + ck * 128 + ks * 32);
      acc0 = __builtin_amdgcn_mfma_f32_16x16x32_bf16(af, b0, acc0, 0, 0, 0);
      acc1 = __builtin_amdgcn_mfma_f32_16x16x32_bf16(af, b1, acc1, 0, 0, 0);
    }
  }
  const float bc0 = bcomb[cb + lr], bc1 = bcomb[cb + 16 + lr];
  float ps0 = 0.f, pq0 = 0.f, ps1 = 0.f, pq1 = 0.f;
#pragma unroll
  for (int r = 0; r < 4; ++r) {
    const int row = g * 4 + r;
    const float o0 = acc0[r] + bc0;
    const float o1 = acc1[r] + bc1;
    outl[(size_t)(row0 + row) * 128 + cb + lr] = o0;
    outl[(size_t)(row0 + row) * 128 + cb + 16 + lr] = o1;
    ps0 += o0; pq0 = fmaf(o0, o0, pq0);
    ps1 += o1; pq1 = fmaf(o1, o1, pq1);
  }
#pragma unroll
  for (int m = 16; m <= 32; m <<= 1) {
    ps0 += __shfl_xor(ps0, m); pq0 += __shfl_xor(pq0, m);
    ps1 += __shfl_xor(ps1, m); pq1 += __shfl_xor(pq1, m);
  }
  if (g == 0) {
    psum[blk * 128 + cb + lr] = ps0;       psq[blk * 128 + cb + lr] = pq0;
    psum[blk * 128 + cb + 16 + lr] = ps1;  psq[blk * 128 + cb + 16 + lr] = pq1;
  }
}

// ---- k3: fused GraphNorm stats + normalize + relu + residual ----
__global__ __launch_bounds__(256) void k_apply(
    const float* __restrict__ psum, const float* __restrict__ psq,
    const float* __restrict__ outl, const float* __restrict__ x,
    const float* __restrict__ gw, const float* __restrict__ gb,
    const float* __restrict__ alpha, float* __restrict__ y) {
  __shared__ float red[4][CC];
  __shared__ float smu[CC], siv[CC];
  const int t = threadIdx.x;
  const int c = t & (CC - 1);
  const int h = t >> 7;   // 0/1
  float s = 0.f, q = 0.f;
#pragma unroll 4
  for (int i = 0; i < 64; ++i) {
    const int r = h * 64 + i;
    s += psum[r * CC + c];
    q += psq[r * CC + c];
  }
  red[h][c] = s; red[2 + h][c] = q;
  __syncthreads();
  if (t < CC) {
    const float ss = red[0][t] + red[1][t];
    const float qq = red[2][t] + red[3][t];
    const float mu = ss * (1.f / 2048.f);
    const float ex2 = qq * (1.f / 2048.f);
    const float amu = alpha[t] * mu;
    const float v = ex2 - 2.f * amu * mu + amu * amu;
    smu[t] = amu;
    siv[t] = gw[t] / sqrtf(v + 1e-5f);
  }
  __syncthreads();
  const int row0 = blockIdx.x * 8;
#pragma unroll
  for (int r = 0; r < 8; r += 2) {
    const int idx = (row0 + r + h) * CC + c;
    const float o = outl[idx];
    const float val = (o - smu[c]) * siv[c] + gb[c];
    y[idx] = fmaxf(val, 0.f) + x[idx];
  }
}

extern "C" void kernel_launch(void* const* d_in, const int* in_sizes, int n_in,
                              void* d_out, int out_size, void* d_ws, size_t ws_size,
                              hipStream_t stream) {
  const float* x      = (const float*)d_in[0];
  const float* edge   = (const float*)d_in[1];
  const float* W_edge = (const float*)d_in[2];
  const float* b_edge = (const float*)d_in[3];
  const float* W_pre  = (const float*)d_in[4];
  const float* b_pre  = (const float*)d_in[5];
  const float* W_post = (const float*)d_in[6];
  const float* b_post = (const float*)d_in[7];
  const float* W_lin  = (const float*)d_in[8];
  const float* b_lin  = (const float*)d_in[9];
  const float* gw     = (const float*)d_in[10];
  const float* gb     = (const float*)d_in[11];
  const float* alpha  = (const float*)d_in[12];
  float* y = (float*)d_out;

  float* wsf = (float*)d_ws;
  float* bc2   = wsf;                          // [0, 128)
  float* At    = wsf + 128;                    // -> 262272
  float* agg   = wsf + 262272;                 // -> 1310848
  float* outl  = wsf + 1310848;                // -> 1572992
  float* psum  = wsf + 1572992;                // 128*128 -> 1589376
  float* psq   = wsf + 1589376;                // -> 1605760
  uint16_t* wct = (uint16_t*)(wsf + 1605760);  // 16384 bf16 -> 1613952
  unsigned* bvl = (unsigned*)(wsf + 1613952);  // 131072 u32 -> 1745024
  uint16_t* wcombT = (uint16_t*)(wsf + 1745024); // 81920 bf16 -> 1785984
  float* bcomb = wsf + 1785984;                // -> 1786112

  k_prep<<<1280, 128, 0, stream>>>(W_edge, b_edge, W_pre, b_pre, W_post, b_post,
                                   W_lin, b_lin, x, wct, bc2, At, bvl, wcombT, bcomb);
  k_edge<<<2048, 256, 0, stream>>>(edge, wct, bvl, At, bc2, agg);
  k_post<<<128, 256, 0, stream>>>(x, agg, wcombT, bcomb, outl, psum, psq);
  k_apply<<<256, 256, 0, stream>>>(psum, psq, outl, x, gw, gb, alpha, y);
}